// Round 1
// baseline (111.816 us; speedup 1.0000x reference)
//
#include <hip/hip_runtime.h>

// OU probability-flow elementwise kernel.
// dz_dt = K*z + K*(-(z - mt)/vart) = c1*z + c0,  c1 = K - K/vart, c0 = K*mt/vart
// dlogp = -D * c1  (broadcast over [B,1])
//
// B=131072, D=512, fp32 in/out. Memory-bound: ~537 MB traffic -> ~90 us @ 6.3 TB/s.

#ifndef OU_K
#define OU_K 1.0f
#define OU_M 1.0f
#define OU_SIGMA 0.5f
#endif

__global__ __launch_bounds__(256) void ou_flow_kernel(
    const float* __restrict__ z,
    const float* __restrict__ t,
    float* __restrict__ dz,      // [B*D]
    float* __restrict__ dlogp,   // [B]
    int n4,                      // (B*D)/4
    int b4)                      // B/4
{
    // Scalar prelude — t[0] is a broadcast load (L1/L2 hit for all waves).
    const float tt = t[0];
    const float omt = 1.0f - tt;
    const float em1 = expf(-OU_K * omt);        // exp(-K(1-t))
    const float em2 = em1 * em1;                // exp(-2K(1-t))
    const float mt = em1 * OU_M;
    // vart = (-1 + exp(2K(1-t)) + sigma^2) * exp(-2K(1-t)) = 1 + (sigma^2-1)*em2
    const float vart = 1.0f + (OU_SIGMA * OU_SIGMA - 1.0f) * em2;
    const float inv_vart = 1.0f / vart;
    const float c1 = OU_K - OU_K * inv_vart;
    const float c0 = OU_K * mt * inv_vart;
    const float dlogp_val = -512.0f * c1;       // -D * c1

    const int stride = gridDim.x * blockDim.x;
    const int tid = blockIdx.x * blockDim.x + threadIdx.x;

    // Main elementwise pass: float4 (16 B/lane) coalesced.
    const float4* __restrict__ z4 = reinterpret_cast<const float4*>(z);
    float4* __restrict__ dz4 = reinterpret_cast<float4*>(dz);
    for (int i = tid; i < n4; i += stride) {
        float4 v = z4[i];
        float4 o;
        o.x = fmaf(c1, v.x, c0);
        o.y = fmaf(c1, v.y, c0);
        o.z = fmaf(c1, v.z, c0);
        o.w = fmaf(c1, v.w, c0);
        dz4[i] = o;
    }

    // dlogp broadcast fill (tiny: 0.5 MiB).
    float4* __restrict__ dlogp4 = reinterpret_cast<float4*>(dlogp);
    const float4 dv = make_float4(dlogp_val, dlogp_val, dlogp_val, dlogp_val);
    for (int i = tid; i < b4; i += stride) {
        dlogp4[i] = dv;
    }
}

extern "C" void kernel_launch(void* const* d_in, const int* in_sizes, int n_in,
                              void* d_out, int out_size, void* d_ws, size_t ws_size,
                              hipStream_t stream) {
    const float* z = (const float*)d_in[0];
    const float* t = (const float*)d_in[1];

    const int B = 131072;
    const int D = 512;
    const int n = B * D;          // 67,108,864
    const int n4 = n / 4;         // 16,777,216
    const int b4 = B / 4;         // 32,768

    float* dz = (float*)d_out;
    float* dlogp = (float*)d_out + n;

    const int block = 256;
    const int grid = 2048;        // 8 blocks/CU on 256 CUs; grid-stride covers the rest

    ou_flow_kernel<<<grid, block, 0, stream>>>(z, t, dz, dlogp, n4, b4);
}